// Round 12
// baseline (516.430 us; speedup 1.0000x reference)
//
#include <hip/hip_runtime.h>
#include <hip/hip_bf16.h>

// Mamba2 mixer — 256² MFMA GEMMs (ring-9 LDS, counted vmcnt, split-K out-proj),
// strip-balanced MFMA chunk_out, MFMA chunk_states.
// B=2 S=2048 HID=2048 INTER=4096 NH=64 HD=64 NG=8 SS=128 CK=4 CH=256 NC=8

#define S_LEN 2048
#define HIDDEN 2048
#define INTER 4096
#define NH 64
#define HD 64
#define NG 8
#define SSZ 128
#define CONV_DIM 6144
#define PROJ_DIM 10304
#define PROJ_PAD 10496     // 41*256
#define NC 8
#define CHK 256
#define ROWS 4096          // B*S
#define DT_OFF 10240       // INTER + CONV_DIM
#define B_OFF 4096         // B section inside conv block
#define C_OFF 5120         // C section inside conv block

typedef __hip_bfloat16 bf16;
typedef __attribute__((ext_vector_type(8))) short bf16x8;
typedef __attribute__((ext_vector_type(4))) float f32x4;
#define MFMA16(a, b, c) __builtin_amdgcn_mfma_f32_16x16x32_bf16(a, b, c, 0, 0, 0)

union U16x8 { uint4 u; bf16x8 v; };

__device__ __forceinline__ float siluf(float x) { return x / (1.f + __expf(-x)); }
__device__ __forceinline__ float ldf(const float* p) { return *p; }
__device__ __forceinline__ float ldf(const bf16* p) { return __bfloat162float(*p); }
__device__ __forceinline__ unsigned short f2bu(float x) {
  bf16 h = __float2bfloat16(x);
  return __builtin_bit_cast(unsigned short, h);
}
__device__ __forceinline__ float bu2f(unsigned short u) {
  return __uint_as_float(((unsigned)u) << 16);
}
__device__ __forceinline__ unsigned pack2(float lo, float hi) {
  return ((unsigned)f2bu(hi) << 16) | f2bu(lo);
}
// async global->LDS, 16B per lane; LDS dst wave-uniform (HW adds lane*16)
__device__ __forceinline__ void gload16(const void* g, void* l) {
  __builtin_amdgcn_global_load_lds((const __attribute__((address_space(1))) unsigned*)g,
                                   (__attribute__((address_space(3))) unsigned*)l, 16, 0, 0);
}

// ---------------- fp32 -> bf16 bulk convert ----------------
__global__ __launch_bounds__(256) void cvt_bf16_k(const float* __restrict__ x,
                                                  unsigned short* __restrict__ o, int n4) {
  int idx = blockIdx.x * 256 + threadIdx.x;
  int stride = gridDim.x * 256;
  for (int i = idx; i < n4; i += stride) {
    float4 v = reinterpret_cast<const float4*>(x)[i];
    uint2 u = make_uint2(pack2(v.x, v.y), pack2(v.z, v.w));
    reinterpret_cast<uint2*>(o)[i] = u;
  }
}

// ---------------- split-K reduce: out = p0 + p1 ----------------
__global__ __launch_bounds__(256) void add_k(const float* __restrict__ p0,
                                             const float* __restrict__ p1,
                                             float* __restrict__ o, int n4) {
  int idx = blockIdx.x * 256 + threadIdx.x;
  int stride = gridDim.x * 256;
  for (int i = idx; i < n4; i += stride) {
    float4 a = reinterpret_cast<const float4*>(p0)[i];
    float4 b = reinterpret_cast<const float4*>(p1)[i];
    reinterpret_cast<float4*>(o)[i] =
        make_float4(a.x + b.x, a.y + b.y, a.z + b.z, a.w + b.w);
  }
}

// ------------- weight transpose+convert: W[K][N] f32 -> Wt[NP][K] bf16 ----------
__global__ __launch_bounds__(256) void wT_k(const float* __restrict__ W,
                                            unsigned short* __restrict__ Wt,
                                            int K, int N) {
  __shared__ unsigned short t[64][72];
  int n0 = blockIdx.x * 64, k0 = blockIdx.y * 64;
  int tid = threadIdx.x;
  const int fr = tid >> 4;
  const int fc = tid & 15;
#pragma unroll
  for (int i = 0; i < 4; ++i) {
    int kr = fr + i * 16;
    int nc = fc * 4;
    int ng = n0 + nc;
    float4 v = (ng < N) ? *reinterpret_cast<const float4*>(&W[(size_t)(k0 + kr) * N + ng])
                        : make_float4(0.f, 0.f, 0.f, 0.f);
    t[kr][nc] = f2bu(v.x); t[kr][nc + 1] = f2bu(v.y);
    t[kr][nc + 2] = f2bu(v.z); t[kr][nc + 3] = f2bu(v.w);
  }
  __syncthreads();
#pragma unroll
  for (int i = 0; i < 2; ++i) {
    int item = tid + i * 256;
    int nr = item >> 3;
    int kc8 = (item & 7) * 8;
    unsigned short vals[8];
#pragma unroll
    for (int ei = 0; ei < 8; ++ei) {
      int e = ei ^ (tid & 7);
      vals[e] = t[kc8 + e][nr];
    }
    *reinterpret_cast<uint4*>(&Wt[(size_t)(n0 + nr) * K + k0 + kc8]) =
        *reinterpret_cast<const uint4*>(vals);
  }
}

// =========================== 256² ring-9 GEMM (r10 form) =====================
__device__ __forceinline__ int mod9(int x) { return x >= 9 ? x - 9 : x; }

__device__ __forceinline__ void stage_half(const unsigned short* __restrict__ A,
                                           const unsigned short* __restrict__ Bt,
                                           unsigned short* lds9, int hj, int slot,
                                           int m0, int n0, int K, int kbase, int hmax,
                                           int tid, int wid) {
  if (hj >= hmax) return;
  const int t = hj >> 2, i = hj & 3;
  const unsigned short* src = (i < 2) ? A : Bt;
  const int br = ((i < 2) ? m0 : n0) + (i & 1) * 128;
  const int g = (tid & 7) ^ ((tid >> 3) & 7);
#pragma unroll
  for (int r = 0; r < 2; ++r) {
    int row = r * 64 + (tid >> 3);
    gload16(&src[(size_t)(br + row) * K + kbase + t * 64 + g * 8],
            &lds9[slot * 8192 + r * 4096 + wid * 512]);
  }
}

template <typename TC>
__global__ __launch_bounds__(512, 2) void gemm_8ph(const unsigned short* __restrict__ A,
                                                   const unsigned short* __restrict__ Bt,
                                                   TC* __restrict__ C,
                                                   int M, int N, int K, int ksplit) {
  extern __shared__ unsigned short lds9[];
  const int tid = threadIdx.x;
  const int lane = tid & 63, hi = lane >> 4, sl = lane & 15;
  const int wid = tid >> 6;
  const int wm = wid >> 2, wn = wid & 3;
  const int gx = gridDim.x;
  int lin = blockIdx.y * gx + blockIdx.x;
  int cpx = (gx * gridDim.y) >> 3;
  int swz = (lin & 7) * cpx + (lin >> 3);
  const int m0 = (swz / gx) * 256;
  const int n0 = (swz % gx) * 256;
  const int kbase = blockIdx.z * ksplit;
  TC* Cz = C + (size_t)blockIdx.z * M * N;
  const int NT = ksplit >> 6;
  const int HMAX = NT << 2;
  const int rbB = (wn & 1) * 64;

  f32x4 acc[8][4] = {};
  bf16x8 a0[4][2], a1[4][2], bb[4][2];

#pragma unroll
  for (int j = 0; j < 5; ++j)
    stage_half(A, Bt, lds9, j, j, m0, n0, K, kbase, HMAX, tid, wid);

  int j0 = 0;
  for (int t = 0; t < NT; ++t) {
    const int sAw = mod9(j0 + wm);
    const int sBw = mod9(j0 + 2 + (wn >> 1));
    if (4 * t + 4 < HMAX) { asm volatile("s_waitcnt vmcnt(2)" ::: "memory"); }
    else                  { asm volatile("s_waitcnt vmcnt(0)" ::: "memory"); }
    __builtin_amdgcn_sched_barrier(0);
    __builtin_amdgcn_s_barrier();
    __builtin_amdgcn_sched_barrier(0);
    // ---- phase 1 ----
#pragma unroll
    for (int mf = 0; mf < 4; ++mf)
#pragma unroll
      for (int kk = 0; kk < 2; ++kk) {
        int ra = mf * 16 + sl;
        a0[mf][kk] = *reinterpret_cast<const bf16x8*>(
            &lds9[sAw * 8192 + ra * 64 + (((kk * 4 + hi) ^ (ra & 7)) * 8)]);
      }
#pragma unroll
    for (int nf = 0; nf < 2; ++nf)
#pragma unroll
      for (int kk = 0; kk < 2; ++kk) {
        int rb = rbB + nf * 16 + sl;
        bb[nf][kk] = *reinterpret_cast<const bf16x8*>(
            &lds9[sBw * 8192 + rb * 64 + (((kk * 4 + hi) ^ (rb & 7)) * 8)]);
      }
    stage_half(A, Bt, lds9, 4 * t + 5, mod9(j0 + 5), m0, n0, K, kbase, HMAX, tid, wid);
    asm volatile("s_waitcnt lgkmcnt(0)" ::: "memory");
    __builtin_amdgcn_sched_barrier(0);
    __builtin_amdgcn_s_setprio(1);
#pragma unroll
    for (int mf = 0; mf < 4; ++mf)
#pragma unroll
      for (int nf = 0; nf < 2; ++nf)
#pragma unroll
        for (int kk = 0; kk < 2; ++kk)
          acc[mf][nf] = MFMA16(a0[mf][kk], bb[nf][kk], acc[mf][nf]);
    __builtin_amdgcn_s_setprio(0);
    __builtin_amdgcn_sched_barrier(0);
    // ---- phase 2 ----
#pragma unroll
    for (int nf = 2; nf < 4; ++nf)
#pragma unroll
      for (int kk = 0; kk < 2; ++kk) {
        int rb = rbB + nf * 16 + sl;
        bb[nf][kk] = *reinterpret_cast<const bf16x8*>(
            &lds9[sBw * 8192 + rb * 64 + (((kk * 4 + hi) ^ (rb & 7)) * 8)]);
      }
    stage_half(A, Bt, lds9, 4 * t + 6, mod9(j0 + 6), m0, n0, K, kbase, HMAX, tid, wid);
    asm volatile("s_waitcnt lgkmcnt(0)" ::: "memory");
    __builtin_amdgcn_sched_barrier(0);
    __builtin_amdgcn_s_setprio(1);
#pragma unroll
    for (int mf = 0; mf < 4; ++mf)
#pragma unroll
      for (int nf = 2; nf < 4; ++nf)
#pragma unroll
        for (int kk = 0; kk < 2; ++kk)
          acc[mf][nf] = MFMA16(a0[mf][kk], bb[nf][kk], acc[mf][nf]);
    __builtin_amdgcn_s_setprio(0);
    __builtin_amdgcn_sched_barrier(0);
    // ---- phase 3 ----
#pragma unroll
    for (int mf = 0; mf < 4; ++mf)
#pragma unroll
      for (int kk = 0; kk < 2; ++kk) {
        int ra = (mf + 4) * 16 + sl;
        a1[mf][kk] = *reinterpret_cast<const bf16x8*>(
            &lds9[sAw * 8192 + ra * 64 + (((kk * 4 + hi) ^ (ra & 7)) * 8)]);
      }
    stage_half(A, Bt, lds9, 4 * t + 7, mod9(j0 + 7), m0, n0, K, kbase, HMAX, tid, wid);
    asm volatile("s_waitcnt lgkmcnt(0)" ::: "memory");
    __builtin_amdgcn_sched_barrier(0);
    __builtin_amdgcn_s_setprio(1);
#pragma unroll
    for (int mf = 0; mf < 4; ++mf)
#pragma unroll
      for (int nf = 0; nf < 2; ++nf)
#pragma unroll
        for (int kk = 0; kk < 2; ++kk)
          acc[mf + 4][nf] = MFMA16(a1[mf][kk], bb[nf][kk], acc[mf + 4][nf]);
    __builtin_amdgcn_s_setprio(0);
    __builtin_amdgcn_sched_barrier(0);
    // ---- phase 4 ----
    stage_half(A, Bt, lds9, 4 * t + 8, mod9(j0 + 8), m0, n0, K, kbase, HMAX, tid, wid);
    __builtin_amdgcn_s_setprio(1);
#pragma unroll
    for (int mf = 0; mf < 4; ++mf)
#pragma unroll
      for (int nf = 2; nf < 4; ++nf)
#pragma unroll
        for (int kk = 0; kk < 2; ++kk)
          acc[mf + 4][nf] = MFMA16(a1[mf][kk], bb[nf][kk], acc[mf + 4][nf]);
    __builtin_amdgcn_s_setprio(0);
    __builtin_amdgcn_sched_barrier(0);
    j0 += 4; if (j0 >= 9) j0 -= 9;
  }
#pragma unroll
  for (int mf = 0; mf < 8; ++mf)
#pragma unroll
    for (int nf = 0; nf < 4; ++nf) {
      int col = n0 + wn * 64 + nf * 16 + sl;
      if (col < N) {
#pragma unroll
        for (int r = 0; r < 4; ++r) {
          int row = m0 + wm * 128 + mf * 16 + hi * 4 + r;
          if constexpr (sizeof(TC) == 2)
            Cz[(size_t)row * N + col] = __float2bfloat16(acc[mf][nf][r]);
          else
            Cz[(size_t)row * N + col] = acc[mf][nf][r];
        }
      }
    }
}

// ------------- depthwise conv (SAME, k=4, pad_lo=1) + SiLU, bf16x8 ----------
__global__ __launch_bounds__(256) void conv_silu_k(const bf16* __restrict__ proj,
                                                   const float* __restrict__ cw,
                                                   const float* __restrict__ cb,
                                                   bf16* __restrict__ convo) {
  int idx = blockIdx.x * 256 + threadIdx.x;
  int ci = idx % (CONV_DIM / 8);
  int row = idx / (CONV_DIM / 8);
  int c8 = ci * 8;
  int t = row & (S_LEN - 1);
  int b = row >> 11;
  float acc[8];
  {
    float4 b0 = *reinterpret_cast<const float4*>(&cb[c8]);
    float4 b1 = *reinterpret_cast<const float4*>(&cb[c8 + 4]);
    acc[0] = b0.x; acc[1] = b0.y; acc[2] = b0.z; acc[3] = b0.w;
    acc[4] = b1.x; acc[5] = b1.y; acc[6] = b1.z; acc[7] = b1.w;
  }
#pragma unroll
  for (int w = 0; w < 4; w++) {
    int tt = t + w - 1;
    if (tt >= 0 && tt < S_LEN) {
      U16x8 u;
      u.u = *reinterpret_cast<const uint4*>(
          &proj[(size_t)(b * S_LEN + tt) * PROJ_DIM + INTER + c8]);
      float4 w0 = *reinterpret_cast<const float4*>(&cw[w * CONV_DIM + c8]);
      float4 w1 = *reinterpret_cast<const float4*>(&cw[w * CONV_DIM + c8 + 4]);
      acc[0] += w0.x * bu2f((unsigned short)u.v[0]);
      acc[1] += w0.y * bu2f((unsigned short)u.v[1]);
      acc[2] += w0.z * bu2f((unsigned short)u.v[2]);
      acc[3] += w0.w * bu2f((unsigned short)u.v[3]);
      acc[4] += w1.x * bu2f((unsigned short)u.v[4]);
      acc[5] += w1.y * bu2f((unsigned short)u.v[5]);
      acc[6] += w1.z * bu2f((unsigned short)u.v[6]);
      acc[7] += w1.w * bu2f((unsigned short)u.v[7]);
    }
  }
  uint4 o;
  o.x = pack2(siluf(acc[0]), siluf(acc[1]));
  o.y = pack2(siluf(acc[2]), siluf(acc[3]));
  o.z = pack2(siluf(acc[4]), siluf(acc[5]));
  o.w = pack2(siluf(acc[6]), siluf(acc[7]));
  *reinterpret_cast<uint4*>(&convo[(size_t)row * CONV_DIM + c8]) = o;
}

// ---------------- dt = softplus(dt_raw + dt_bias) ----------------
__global__ __launch_bounds__(256) void dt_k(const bf16* __restrict__ proj,
                                            const float* __restrict__ dtb,
                                            float* __restrict__ dtp) {
  int idx = blockIdx.x * 256 + threadIdx.x;
  int h = idx & 63;
  int row = idx >> 6;
  float x = ldf(&proj[(size_t)row * PROJ_DIM + DT_OFF + h]) + dtb[h];
  dtp[idx] = (x > 20.f) ? x : log1pf(__expf(x));
}

// ---------------- per-chunk cumsum of A[h]*dt ----------------
__global__ __launch_bounds__(256) void acum_k(const float* __restrict__ dtp,
                                              const float* __restrict__ alog,
                                              float* __restrict__ acum) {
  __shared__ float buf[2][CHK];
  int blk = blockIdx.x;
  int c = blk & 7;
  int h = (blk >> 3) & 63;
  int b = blk >> 9;
  int tid = threadIdx.x;
  int row0 = b * S_LEN + c * CHK;
  float a = -__expf(alog[h]);
  buf[0][tid] = a * dtp[(size_t)(row0 + tid) * NH + h];
  __syncthreads();
  int cur = 0;
#pragma unroll
  for (int off = 1; off < 256; off <<= 1) {
    float nv = buf[cur][tid];
    if (tid >= off) nv += buf[cur][tid - off];
    buf[cur ^ 1][tid] = nv;
    cur ^= 1;
    __syncthreads();
  }
  acum[(size_t)blk * CHK + tid] = buf[cur][tid];
}

// ======== per-chunk states via MFMA ====
__global__ __launch_bounds__(256) void chunk_states_mfma(const bf16* __restrict__ convo,
                                                         const float* __restrict__ dtp,
                                                         const float* __restrict__ acum,
                                                         float* __restrict__ cs) {
  __shared__ float sAc[CHK];
  __shared__ float sDtf[CHK];
  __shared__ float sEx[64];
  __shared__ __align__(16) unsigned short sHT[64 * 64];
  __shared__ __align__(16) unsigned short sBd[128 * 64];
  const int tid = threadIdx.x;
  const int lane = tid & 63, hi = lane >> 4, sl = lane & 15;
  const int wid = tid >> 6, wm = wid >> 1, wn = wid & 1;
  const int blk = blockIdx.x;
  const int h = blk & 63, bc = blk >> 6, c = bc & 7, b = bc >> 3, g = h >> 3;
  const int row0 = b * S_LEN + c * CHK;
  sAc[tid] = acum[((size_t)((b * NH + h) * NC + c)) * CHK + tid];
  sDtf[tid] = dtp[(size_t)(row0 + tid) * NH + h];
  f32x4 acc[2][4] = {};
  for (int ts = 0; ts < 4; ++ts) {
    __syncthreads();
    if (tid < 64) sEx[tid] = __expf(sAc[CHK - 1] - sAc[ts * 64 + tid]);
    __syncthreads();
#pragma unroll
    for (int it = 0; it < 2; ++it) {
      int cid = tid + it * 256;
      int t = cid >> 3, p8 = (cid & 7) * 8;
      U16x8 u;
      u.u = *reinterpret_cast<const uint4*>(
          &convo[(size_t)(row0 + ts * 64 + t) * CONV_DIM + h * HD + p8]);
      float dtv = sDtf[ts * 64 + t];
#pragma unroll
      for (int e = 0; e < 8; ++e) {
        int p = p8 + e;
        int G = (p & 7) ^ ((p >> 3) & 7);
        sHT[p * 64 + (((t >> 3) ^ G) * 8) + (t & 7)] =
            f2bu(bu2f((unsigned short)u.v[e]) * dtv);
      }
    }
#pragma unroll
    for (int it = 0; it < 4; ++it) {
      int cid = tid + it * 256;
      int t = cid >> 4, n8 = (cid & 15) * 8;
      U16x8 u;
      u.u = *reinterpret_cast<const uint4*>(
          &convo[(size_t)(row0 + ts * 64 + t) * CONV_DIM + B_OFF + g * SSZ + n8]);
      float ex = sEx[t];
#pragma unroll
      for (int e = 0; e < 8; ++e) {
        int n = n8 + e;
        int G = (n & 7) ^ ((n >> 3) & 7);
        sBd[n * 64 + (((t >> 3) ^ G) * 8) + (t & 7)] =
            f2bu(bu2f((unsigned short)u.v[e]) * ex);
      }
    }
    __syncthreads();
#pragma unroll
    for (int kc = 0; kc < 2; ++kc) {
      bf16x8 a[2], bb[4];
#pragma unroll
      for (int m = 0; m < 2; ++m) {
        int p = wm * 32 + m * 16 + sl;
        int G = (p & 7) ^ ((p >> 3) & 7);
        a[m] = *reinterpret_cast<const bf16x8*>(
            &sHT[p * 64 + (((kc * 4 + hi) ^ G) * 8)]);
      }
#pragma unroll
      for (int j = 0; j < 4; ++j) {
        int n = wn * 64 + j * 16 + sl;
        int G = (n & 7) ^ ((n >> 3) & 7);
        bb[j] = *reinterpret_cast<const bf16x8*>(
            &sBd[n * 64 + (((kc * 4 + hi) ^ G) * 8)]);
      }
#pragma unroll
      for (int m = 0; m < 2; ++m)
#pragma unroll
        for (int j = 0; j < 4; ++j) acc[m][j] = MFMA16(a[m], bb[j], acc[m][j]);
    }
  }
  size_t base = (size_t)blk * HD * SSZ;
#pragma unroll
  for (int m = 0; m < 2; ++m)
#pragma unroll
    for (int j = 0; j < 4; ++j)
#pragma unroll
      for (int r = 0; r < 4; ++r) {
        int p = wm * 32 + m * 16 + hi * 4 + r;
        int n = wn * 64 + j * 16 + sl;
        cs[base + (size_t)p * SSZ + n] = acc[m][j][r];
      }
}

// ---------------- inter-chunk recurrence (in-place) ----------------
__global__ __launch_bounds__(256) void chunk_rec_k(const float* __restrict__ acum,
                                                   float* __restrict__ cs) {
  int idx = blockIdx.x * 256 + threadIdx.x;
  int n = idx & 127;
  int p = (idx >> 7) & 63;
  int h = (idx >> 13) & 63;
  int b = idx >> 19;
  float run = 0.f;
#pragma unroll
  for (int c = 0; c < NC; c++) {
    size_t off = ((size_t)(((b * NC + c) * NH + h) * HD + p)) * SSZ + n;
    float csv = cs[off];
    float al = acum[((size_t)((b * NH + h) * NC + c)) * CHK + (CHK - 1)];
    cs[off] = run;
    run = run * __expf(al) + csv;
  }
}

// ========== chunk output via MFMA — strip-balanced (8 strips of 32) =========
// Wave w owns l-strips {w, 7-w} -> 9 active strip-pairs per wave (balanced).
// sH: hsdt^T [p][s0..31], granule swz(p)=((p&3)^((p>>2)&3))&3.
// sW: per (wave,slot) [32 l][32 s], granule swz(l). Sin reuses sW in epilogue.
__global__ __launch_bounds__(256) void chunk_out_mfma(const bf16* __restrict__ convo,
                                                      const float* __restrict__ dtp,
                                                      const float* __restrict__ acum,
                                                      const float* __restrict__ cs,
                                                      const float* __restrict__ Dp,
                                                      bf16* __restrict__ yb) {
  __shared__ float sAc[CHK];
  __shared__ float sDt[CHK];
  __shared__ __align__(16) unsigned short sB[32 * 128];   // 8 KB, [s][n] gr^(s&7)
  __shared__ __align__(16) unsigned short sH[64 * 32];    // 4 KB, [p][s]
  __shared__ __align__(16) unsigned short sW[8 * 32 * 32];// 16 KB, W tiles / Sin
  const int tid = threadIdx.x;
  const int lane = tid & 63, hi = lane >> 4, sl = lane & 15;
  const int wid = tid >> 6;
  const int blk = blockIdx.x;
  const int h = blk & 63;
  const int bc = blk >> 6;
  const int c = bc & 7;
  const int b = bc >> 3;
  const int g = h >> 3;
  const int row0 = b * S_LEN + c * CHK;
  const int strips[2] = {wid, 7 - wid};

  sAc[tid] = acum[((size_t)((b * NH + h) * NC + c)) * CHK + tid];
  sDt[tid] = dtp[(size_t)(row0 + tid) * NH + h];

  // C fragments: cf[strip-slot][lf][kc], rows l = strips[t2]*32 + lf*16 + sl
  bf16x8 cf[2][2][4];
#pragma unroll
  for (int t2 = 0; t2 < 2; ++t2)
#pragma unroll
    for (int lf = 0; lf < 2; ++lf)
#pragma unroll
      for (int kc = 0; kc < 4; ++kc) {
        int l = strips[t2] * 32 + lf * 16 + sl;
        U16x8 u;
        u.u = *reinterpret_cast<const uint4*>(
            &convo[(size_t)(row0 + l) * CONV_DIM + C_OFF + g * SSZ + kc * 32 + hi * 8]);
        cf[t2][lf][kc] = u.v;
      }

  f32x4 acc[2][2][4] = {};  // [strip-slot][lf][pf]

  for (int st = 0; st < 8; ++st) {
    __syncthreads();
    // stage sB: 32 s-rows x 128 n (512 granules / 256 thr = 2 each)
#pragma unroll
    for (int it = 0; it < 2; ++it) {
      int cid = tid + it * 256;
      int s = cid >> 4, gr = cid & 15;
      const uint4* p = reinterpret_cast<const uint4*>(
          &convo[(size_t)(row0 + st * 32 + s) * CONV_DIM + B_OFF + g * SSZ + gr * 8]);
      *reinterpret_cast<uint4*>(&sB[s * 128 + (gr ^ (s & 7)) * 8]) = *p;
    }
    // stage sH: [p][s] (2048 elems / 256 thr = 8 each, one uint4 load)
    {
      int s = tid >> 3, p8 = (tid & 7) * 8;
      U16x8 u;
      u.u = *reinterpret_cast<const uint4*>(
          &convo[(size_t)(row0 + st * 32 + s) * CONV_DIM + h * HD + p8]);
      float dtv = sDt[st * 32 + s];
#pragma unroll
      for (int e = 0; e < 8; ++e) {
        int p = p8 + e;
        int sw = ((p & 3) ^ ((p >> 2) & 3)) & 3;
        sH[p * 32 + (((s >> 3) ^ sw) & 3) * 8 + (s & 7)] =
            f2bu(bu2f((unsigned short)u.v[e]) * dtv);
      }
    }
    __syncthreads();
#pragma unroll
    for (int t2 = 0; t2 < 2; ++t2) {
      int is = strips[t2];
      if (st > is) continue;   // wave-uniform
      // scores: d[lf][sf2] over kc
      f32x4 d[2][2] = {};
#pragma unroll
      for (int kc = 0; kc < 4; ++kc) {
        bf16x8 bf2[2];
#pragma unroll
        for (int sf2 = 0; sf2 < 2; ++sf2) {
          int srow = sf2 * 16 + sl;
          bf2[sf2] = *reinterpret_cast<const bf16x8*>(
              &sB[srow * 128 + (((kc * 4 + hi) ^ (srow & 7)) * 8)]);
        }
#pragma unroll
        for (int lf = 0; lf < 2; ++lf)
#pragma unroll
          for (int sf2 = 0; sf2 < 2; ++sf2)
            d[lf][sf2] = MFMA16(cf[t2][lf][kc], bf2[sf2], d[lf][sf2]);
      }
      // mask + decay + write W tile
      unsigned short* sWp = &sW[(wid * 2 + t2) * 1024];
      bool diag = (st == is);
#pragma unroll
      for (int lf = 0; lf < 2; ++lf)
#pragma unroll
        for (int sf2 = 0; sf2 < 2; ++sf2) {
          int s_loc = sf2 * 16 + sl;
          int s_glob = st * 32 + s_loc;
          float acS = sAc[s_glob];
#pragma unroll
          for (int r = 0; r < 4; ++r) {
            int l_loc = lf * 16 + hi * 4 + r;
            int l_glob = is * 32 + l_loc;
            float e = __expf(sAc[l_glob] - acS);
            float v = d[lf][sf2][r] * e;
            if (diag && s_glob > l_glob) v = 0.f;
            int sw = ((l_loc & 3) ^ ((l_loc >> 2) & 3)) & 3;
            sWp[l_loc * 32 + (((s_loc >> 3) ^ sw) & 3) * 8 + (s_loc & 7)] = f2bu(v);
          }
        }
      asm volatile("s_waitcnt lgkmcnt(0)" ::: "memory");
      __builtin_amdgcn_sched_barrier(0);
      // PV: acc[t2] += W(32l x 32s) * hsdt^T(s x 64p)
      bf16x8 aw[2], bh[4];
#pragma unroll
      for (int lf = 0; lf < 2; ++lf) {
        int l = lf * 16 + sl;
        int sw = ((l & 3) ^ ((l >> 2) & 3)) & 3;
        aw[lf] = *reinterpret_cast<const bf16x8*>(
            &sWp[l * 32 + ((hi ^ sw) & 3) * 8]);
      }
#pragma unroll
      for (int pf = 0; pf < 4; ++pf) {
        int p = pf * 16 + sl;
        int sw = ((p & 3) ^ ((p >> 2) & 3)) & 3;
        bh[pf] = *reinterpret_cast<const bf16x8*>(
            &sH[p * 32 + ((hi ^ sw) & 3) * 8]);
      }
#pragma unroll
      for (int lf = 0; lf < 2; ++lf)
#pragma unroll
        for (int pf = 0; pf < 4; ++pf)
          acc[t2][lf][pf] = MFMA16(aw[lf], bh[pf], acc[t2][lf][pf]);
    }
  }

  // ---- epilogue: Sin into sW [64][128] (16 KB), Y_off, D*hs, store ----
  __syncthreads();
  {
    size_t sinbase = ((size_t)(((b * NC + c) * NH + h) * HD)) * SSZ;
#pragma unroll
    for (int it = 0; it < 8; ++it) {
      int cid = tid + it * 256;
      int p = cid >> 5, q = cid & 31;
      float4 v = *reinterpret_cast<const float4*>(&cs[sinbase + (size_t)p * SSZ + q * 4]);
      uint2 val = make_uint2(pack2(v.x, v.y), pack2(v.z, v.w));
      *reinterpret_cast<uint2*>(&sW[p * 128 + ((q >> 1) ^ (p & 7)) * 8 + (q & 1) * 4]) = val;
    }
  }
  __syncthreads();
  // pre-scale cf by exp(Ac[l]) (row-uniform per lane)
#pragma unroll
  for (int t2 = 0; t2 < 2; ++t2)
#pragma unroll
    for (int lf = 0; lf < 2; ++lf) {
      float e = __expf(sAc[strips[t2] * 32 + lf * 16 + sl]);
#pragma unroll
      for (int kc = 0; kc < 4; ++kc) {
        bf16x8 fv = cf[t2][lf][kc];
#pragma unroll
        for (int ei = 0; ei < 8; ++ei) {
          unsigned short us = (unsigned short)fv[ei];
          fv[ei] = (short)f2bu(bu2f(us) * e);
        }
        cf[t2][lf][kc] = fv;
      }
    }
#pragma unroll
  for (int kc = 0; kc < 4; ++kc) {
    bf16x8 bs[4];
#pragma unroll
    for (int pf = 0; pf < 4; ++pf) {
      int p = pf * 16 + sl;
      bs[pf] = *reinterpret_cast<const bf16x8*>(
          &sW[p * 128 + (((kc * 4 + hi) ^ (p & 7)) * 8)]);
    }
#pragma unroll
    for (int t2 = 0; t2 < 2; ++t2)
#pragma unroll
      for (int lf = 0; lf < 2; ++lf)
#pragma unroll
        for (int pf = 0; pf < 4; ++pf)
          acc[t2][lf][pf] = MFMA16(cf[t2][lf][kc], bs[pf], acc[t2][lf][pf]);
  }

  float Dh = Dp[h];
#pragma unroll
  for (int t2 = 0; t2 < 2; ++t2)
#pragma unroll
    for (int lf = 0; lf < 2; ++lf)
#pragma unroll
      for (int pf = 0; pf < 4; ++pf)
#pragma unroll
        for (int r = 0; r < 4; ++r) {
          int l_glob = strips[t2] * 32 + lf * 16 + hi * 4 + r;
          size_t row = (size_t)(row0 + l_glob);
          int pg = pf * 16 + sl;
          float hraw = ldf(&convo[row * CONV_DIM + h * HD + pg]);
          yb[row * INTER + h * HD + pg] =
              __float2bfloat16(acc[t2][lf][pf][r] + Dh * hraw);
        }
}

// ------------- gate SiLU + RMSNorm (in-place on yb), bf16x8 -------------
__global__ __launch_bounds__(256) void norm_k(const bf16* __restrict__ proj,
                                              const float* __restrict__ nw,
                                              bf16* __restrict__ yb) {
  int row = blockIdx.x;
  int tid = threadIdx.x;
  float vals[16];
  float ss = 0.f;
#pragma unroll
  for (int half = 0; half < 2; half++) {
    int colb = tid * 8 + half * 2048;
    U16x8 gy, gg;
    gy.u = *reinterpret_cast<const uint4*>(&yb[(size_t)row * INTER + colb]);
    gg.u = *reinterpret_cast<const uint4*>(&proj[(size_t)row * PROJ_DIM + colb]);
#pragma unroll
    for (int e = 0; e < 8; e++) {
      float yf = bu2f((unsigned short)gy.v[e]) * siluf(bu2f((unsigned short)gg.v[e]));
      vals[half * 8 + e] = yf;
      ss += yf * yf;
    }
  }
#pragma unroll
  for (int off = 32; off > 0; off >>= 1) ss += __shfl_down(ss, off);
  __shared__ float red[4];
  if ((tid & 63) == 0) red[tid >> 6] = ss;
  __syncthreads();
  float tot = red[0] + red[1] + red[2] + red[3];
  float scale = rsqrtf(tot * (1.f / INTER) + 1e-6f);
#pragma unroll
  for (int half = 0; half < 2; half++) {
    int colb = tid * 8 + half * 2048;
    float4 w0 = *reinterpret_cast<const float4*>(&nw[colb]);
    float4 w1 = *reinterpret_cast<const float4*>(&nw[colb + 4]);
    float s0 = vals[half * 8 + 0] * scale * w0.x, s1 = vals[half * 8 + 1] * scale * w0.y;
    float s2 = vals[half * 8 + 2] * scale * w0.z, s3 = vals[half * 8 + 3] * scale * w0.w;
    float s4 = vals[half * 8 + 4] * scale * w1.x, s5 = vals[half * 8 + 5] * scale * w1.y;
    float s6 = vals[half * 8 + 6] * scale * w1.z, s7 = vals[half * 8 + 7] * scale * w1.w;
    uint4 o = make_uint4(pack2(s0, s1), pack2(s2, s3), pack2(s4, s5), pack2(s6, s7));
    *reinterpret_cast<uint4*>(&yb[(size_t)row * INTER + colb]) = o;
  }
}

extern "C" void kernel_launch(void* const* d_in, const int* in_sizes, int n_in,
                              void* d_out, int out_size, void* d_ws, size_t ws_size,
                              hipStream_t stream) {
  const float* x     = (const float*)d_in[0];
  const float* wproj = (const float*)d_in[1];
  const float* cw    = (const float*)d_in[2];
  const float* cb    = (const float*)d_in[3];
  const float* dtb   = (const float*)d_in[4];
  const float* alog  = (const float*)d_in[5];
  const float* Dp    = (const float*)d_in[6];
  const float* nw    = (const float*)d_in[7];
  const float* wout  = (const float*)d_in[8];
  float* out = (float*)d_out;
  char* ws = (char*)d_ws;

  // persistent layout (~195 MiB, proven safe)
  bf16*  proj  = (bf16*)(ws);                    // 84,410,368 B
  bf16*  convo = (bf16*)(ws + 84410368);         // 50,331,648 B
  bf16*  yb    = (bf16*)(ws + 134742016);        // 33,554,432 B
  float* dtp   = (float*)(ws + 168296448);       //  1,048,576 B
  float* acum  = (float*)(ws + 169345024);       //  1,048,576 B
  float* cs    = (float*)(ws + 170393600);       // 33,554,432 B
  // liveness-overlapped temporaries:
  unsigned short* Wt1 = (unsigned short*)(ws + 84410368);   // in convo
  unsigned short* xb  = (unsigned short*)(ws + 134742016);  // in yb
  unsigned short* Wt2 = (unsigned short*)(ws + 170393600);  // in cs
  float* part = (float*)(ws);   // split-K partials in proj region

  hipFuncSetAttribute(reinterpret_cast<const void*>(&gemm_8ph<bf16>),
                      hipFuncAttributeMaxDynamicSharedMemorySize, 147456);
  hipFuncSetAttribute(reinterpret_cast<const void*>(&gemm_8ph<float>),
                      hipFuncAttributeMaxDynamicSharedMemorySize, 147456);

  cvt_bf16_k<<<dim3(2048), 256, 0, stream>>>(x, xb, ROWS * HIDDEN / 4);
  wT_k<<<dim3(PROJ_PAD / 64, HIDDEN / 64), 256, 0, stream>>>(wproj, Wt1, HIDDEN, PROJ_DIM);
  gemm_8ph<bf16><<<dim3(PROJ_PAD / 256, ROWS / 256, 1), 512, 147456, stream>>>(
      xb, Wt1, proj, ROWS, PROJ_DIM, HIDDEN, HIDDEN);
  conv_silu_k<<<dim3(ROWS * CONV_DIM / 8 / 256), 256, 0, stream>>>(proj, cw, cb, convo);
  dt_k<<<dim3(ROWS * NH / 256), 256, 0, stream>>>(proj, dtb, dtp);
  acum_k<<<dim3(2 * NH * NC), 256, 0, stream>>>(dtp, alog, acum);
  chunk_states_mfma<<<dim3(2 * NC * NH), 256, 0, stream>>>(convo, dtp, acum, cs);
  chunk_rec_k<<<dim3(2 * NH * HD * SSZ / 256), 256, 0, stream>>>(acum, cs);
  chunk_out_mfma<<<dim3(2 * NC * NH), 256, 0, stream>>>(convo, dtp, acum, cs, Dp, yb);
  norm_k<<<dim3(ROWS), 256, 0, stream>>>(proj, nw, yb);
  wT_k<<<dim3(HIDDEN / 64, INTER / 64), 256, 0, stream>>>(wout, Wt2, INTER, HIDDEN);
  gemm_8ph<float><<<dim3(HIDDEN / 256, ROWS / 256, 2), 512, 147456, stream>>>(
      (const unsigned short*)yb, Wt2, part, ROWS, HIDDEN, INTER, INTER / 2);
  add_k<<<dim3(2048), 256, 0, stream>>>(part, part + (size_t)ROWS * HIDDEN, out,
                                        ROWS * HIDDEN / 4);
}

// Round 13
// 504.696 us; speedup vs baseline: 1.0232x; 1.0232x over previous
//
#include <hip/hip_runtime.h>
#include <hip/hip_bf16.h>

// Mamba2 mixer — 256² MFMA GEMMs (ring-9 LDS, counted vmcnt, split-K out-proj,
// NON-power-of-2 operand strides to break L2 channel aliasing), MFMA
// chunk_out (r10 proven form) / chunk_states.
// B=2 S=2048 HID=2048 INTER=4096 NH=64 HD=64 NG=8 SS=128 CK=4 CH=256 NC=8

#define S_LEN 2048
#define HIDDEN 2048
#define INTER 4096
#define NH 64
#define HD 64
#define NG 8
#define SSZ 128
#define CONV_DIM 6144
#define PROJ_DIM 10304
#define PROJ_PAD 10496     // 41*256
#define NC 8
#define CHK 256
#define ROWS 4096          // B*S
#define DT_OFF 10240       // INTER + CONV_DIM
#define B_OFF 4096         // B section inside conv block
#define C_OFF 5120         // C section inside conv block
#define XSTR 2112          // xb / Wt1 row stride (2048+64, breaks 4KB pow2)
#define YSTR 4160          // yb / Wt2 row stride (4096+64, breaks 8KB pow2)

typedef __hip_bfloat16 bf16;
typedef __attribute__((ext_vector_type(8))) short bf16x8;
typedef __attribute__((ext_vector_type(4))) float f32x4;
#define MFMA16(a, b, c) __builtin_amdgcn_mfma_f32_16x16x32_bf16(a, b, c, 0, 0, 0)

union U16x8 { uint4 u; bf16x8 v; };

__device__ __forceinline__ float siluf(float x) { return x / (1.f + __expf(-x)); }
__device__ __forceinline__ float ldf(const float* p) { return *p; }
__device__ __forceinline__ float ldf(const bf16* p) { return __bfloat162float(*p); }
__device__ __forceinline__ unsigned short f2bu(float x) {
  bf16 h = __float2bfloat16(x);
  return __builtin_bit_cast(unsigned short, h);
}
__device__ __forceinline__ float bu2f(unsigned short u) {
  return __uint_as_float(((unsigned)u) << 16);
}
__device__ __forceinline__ unsigned pack2(float lo, float hi) {
  return ((unsigned)f2bu(hi) << 16) | f2bu(lo);
}
// async global->LDS, 16B per lane; LDS dst wave-uniform (HW adds lane*16)
__device__ __forceinline__ void gload16(const void* g, void* l) {
  __builtin_amdgcn_global_load_lds((const __attribute__((address_space(1))) unsigned*)g,
                                   (__attribute__((address_space(3))) unsigned*)l, 16, 0, 0);
}

// -------- fp32 [4096][2048] -> bf16 [4096][XSTR] (padded rows) --------
__global__ __launch_bounds__(256) void cvt_pad_k(const float* __restrict__ x,
                                                 unsigned short* __restrict__ o) {
  int idx = blockIdx.x * 256 + threadIdx.x;   // 4096*256
  int row = idx >> 8;
  int c8 = (idx & 255) * 8;
  float4 v0 = *reinterpret_cast<const float4*>(&x[(size_t)row * HIDDEN + c8]);
  float4 v1 = *reinterpret_cast<const float4*>(&x[(size_t)row * HIDDEN + c8 + 4]);
  uint4 u = make_uint4(pack2(v0.x, v0.y), pack2(v0.z, v0.w),
                       pack2(v1.x, v1.y), pack2(v1.z, v1.w));
  *reinterpret_cast<uint4*>(&o[(size_t)row * XSTR + c8]) = u;
}

// ---------------- split-K reduce: out = p0 + p1 ----------------
__global__ __launch_bounds__(256) void add_k(const float* __restrict__ p0,
                                             const float* __restrict__ p1,
                                             float* __restrict__ o, int n4) {
  int idx = blockIdx.x * 256 + threadIdx.x;
  int stride = gridDim.x * 256;
  for (int i = idx; i < n4; i += stride) {
    float4 a = reinterpret_cast<const float4*>(p0)[i];
    float4 b = reinterpret_cast<const float4*>(p1)[i];
    reinterpret_cast<float4*>(o)[i] =
        make_float4(a.x + b.x, a.y + b.y, a.z + b.z, a.w + b.w);
  }
}

// ---- weight transpose+convert: W[K][N] f32 -> Wt[NP][ldw] bf16 (padded) ----
__global__ __launch_bounds__(256) void wT_k(const float* __restrict__ W,
                                            unsigned short* __restrict__ Wt,
                                            int K, int N, int ldw) {
  __shared__ unsigned short t[64][72];
  int n0 = blockIdx.x * 64, k0 = blockIdx.y * 64;
  int tid = threadIdx.x;
  const int fr = tid >> 4;
  const int fc = tid & 15;
#pragma unroll
  for (int i = 0; i < 4; ++i) {
    int kr = fr + i * 16;
    int nc = fc * 4;
    int ng = n0 + nc;
    float4 v = (ng < N) ? *reinterpret_cast<const float4*>(&W[(size_t)(k0 + kr) * N + ng])
                        : make_float4(0.f, 0.f, 0.f, 0.f);
    t[kr][nc] = f2bu(v.x); t[kr][nc + 1] = f2bu(v.y);
    t[kr][nc + 2] = f2bu(v.z); t[kr][nc + 3] = f2bu(v.w);
  }
  __syncthreads();
#pragma unroll
  for (int i = 0; i < 2; ++i) {
    int item = tid + i * 256;
    int nr = item >> 3;
    int kc8 = (item & 7) * 8;
    unsigned short vals[8];
#pragma unroll
    for (int ei = 0; ei < 8; ++ei) {
      int e = ei ^ (tid & 7);
      vals[e] = t[kc8 + e][nr];
    }
    *reinterpret_cast<uint4*>(&Wt[(size_t)(n0 + nr) * ldw + k0 + kc8]) =
        *reinterpret_cast<const uint4*>(vals);
  }
}

// =========================== 256² ring-9 GEMM ===============================
// C[M,N] = A[M,*lda] @ Bt[N,*ldb]^T over K-range [z*ksplit,(z+1)*ksplit).
__device__ __forceinline__ int mod9(int x) { return x >= 9 ? x - 9 : x; }

__device__ __forceinline__ void stage_half(const unsigned short* __restrict__ A,
                                           const unsigned short* __restrict__ Bt,
                                           unsigned short* lds9, int hj, int slot,
                                           int m0, int n0, int lda, int ldb,
                                           int kbase, int hmax, int tid, int wid) {
  if (hj >= hmax) return;
  const int t = hj >> 2, i = hj & 3;
  const unsigned short* src = (i < 2) ? A : Bt;
  const int ld = (i < 2) ? lda : ldb;
  const int br = ((i < 2) ? m0 : n0) + (i & 1) * 128;
  const int g = (tid & 7) ^ ((tid >> 3) & 7);
#pragma unroll
  for (int r = 0; r < 2; ++r) {
    int row = r * 64 + (tid >> 3);
    gload16(&src[(size_t)(br + row) * ld + kbase + t * 64 + g * 8],
            &lds9[slot * 8192 + r * 4096 + wid * 512]);
  }
}

template <typename TC>
__global__ __launch_bounds__(512, 2) void gemm_8ph(const unsigned short* __restrict__ A,
                                                   const unsigned short* __restrict__ Bt,
                                                   TC* __restrict__ C,
                                                   int M, int N, int K, int ksplit,
                                                   int lda, int ldb) {
  extern __shared__ unsigned short lds9[];
  const int tid = threadIdx.x;
  const int lane = tid & 63, hi = lane >> 4, sl = lane & 15;
  const int wid = tid >> 6;
  const int wm = wid >> 2, wn = wid & 3;
  const int gx = gridDim.x;
  int lin = blockIdx.y * gx + blockIdx.x;
  int cpx = (gx * gridDim.y) >> 3;
  int swz = (lin & 7) * cpx + (lin >> 3);
  const int m0 = (swz / gx) * 256;
  const int n0 = (swz % gx) * 256;
  const int kbase = blockIdx.z * ksplit;
  TC* Cz = C + (size_t)blockIdx.z * M * N;
  const int NT = ksplit >> 6;
  const int HMAX = NT << 2;
  const int rbB = (wn & 1) * 64;

  f32x4 acc[8][4] = {};
  bf16x8 a0[4][2], a1[4][2], bb[4][2];

#pragma unroll
  for (int j = 0; j < 5; ++j)
    stage_half(A, Bt, lds9, j, j, m0, n0, lda, ldb, kbase, HMAX, tid, wid);

  int j0 = 0;
  for (int t = 0; t < NT; ++t) {
    const int sAw = mod9(j0 + wm);
    const int sBw = mod9(j0 + 2 + (wn >> 1));
    if (4 * t + 4 < HMAX) { asm volatile("s_waitcnt vmcnt(2)" ::: "memory"); }
    else                  { asm volatile("s_waitcnt vmcnt(0)" ::: "memory"); }
    __builtin_amdgcn_sched_barrier(0);
    __builtin_amdgcn_s_barrier();
    __builtin_amdgcn_sched_barrier(0);
    // ---- phase 1 ----
#pragma unroll
    for (int mf = 0; mf < 4; ++mf)
#pragma unroll
      for (int kk = 0; kk < 2; ++kk) {
        int ra = mf * 16 + sl;
        a0[mf][kk] = *reinterpret_cast<const bf16x8*>(
            &lds9[sAw * 8192 + ra * 64 + (((kk * 4 + hi) ^ (ra & 7)) * 8)]);
      }
#pragma unroll
    for (int nf = 0; nf < 2; ++nf)
#pragma unroll
      for (int kk = 0; kk < 2; ++kk) {
        int rb = rbB + nf * 16 + sl;
        bb[nf][kk] = *reinterpret_cast<const bf16x8*>(
            &lds9[sBw * 8192 + rb * 64 + (((kk * 4 + hi) ^ (rb & 7)) * 8)]);
      }
    stage_half(A, Bt, lds9, 4 * t + 5, mod9(j0 + 5), m0, n0, lda, ldb, kbase, HMAX, tid, wid);
    asm volatile("s_waitcnt lgkmcnt(0)" ::: "memory");
    __builtin_amdgcn_sched_barrier(0);
    __builtin_amdgcn_s_setprio(1);
#pragma unroll
    for (int mf = 0; mf < 4; ++mf)
#pragma unroll
      for (int nf = 0; nf < 2; ++nf)
#pragma unroll
        for (int kk = 0; kk < 2; ++kk)
          acc[mf][nf] = MFMA16(a0[mf][kk], bb[nf][kk], acc[mf][nf]);
    __builtin_amdgcn_s_setprio(0);
    __builtin_amdgcn_sched_barrier(0);
    // ---- phase 2 ----
#pragma unroll
    for (int nf = 2; nf < 4; ++nf)
#pragma unroll
      for (int kk = 0; kk < 2; ++kk) {
        int rb = rbB + nf * 16 + sl;
        bb[nf][kk] = *reinterpret_cast<const bf16x8*>(
            &lds9[sBw * 8192 + rb * 64 + (((kk * 4 + hi) ^ (rb & 7)) * 8)]);
      }
    stage_half(A, Bt, lds9, 4 * t + 6, mod9(j0 + 6), m0, n0, lda, ldb, kbase, HMAX, tid, wid);
    asm volatile("s_waitcnt lgkmcnt(0)" ::: "memory");
    __builtin_amdgcn_sched_barrier(0);
    __builtin_amdgcn_s_setprio(1);
#pragma unroll
    for (int mf = 0; mf < 4; ++mf)
#pragma unroll
      for (int nf = 2; nf < 4; ++nf)
#pragma unroll
        for (int kk = 0; kk < 2; ++kk)
          acc[mf][nf] = MFMA16(a0[mf][kk], bb[nf][kk], acc[mf][nf]);
    __builtin_amdgcn_s_setprio(0);
    __builtin_amdgcn_sched_barrier(0);
    // ---- phase 3 ----
#pragma unroll
    for (int mf = 0; mf < 4; ++mf)
#pragma unroll
      for (int kk = 0; kk < 2; ++kk) {
        int ra = (mf + 4) * 16 + sl;
        a1[mf][kk] = *reinterpret_cast<const bf16x8*>(
            &lds9[sAw * 8192 + ra * 64 + (((kk * 4 + hi) ^ (ra & 7)) * 8)]);
      }
    stage_half(A, Bt, lds9, 4 * t + 7, mod9(j0 + 7), m0, n0, lda, ldb, kbase, HMAX, tid, wid);
    asm volatile("s_waitcnt lgkmcnt(0)" ::: "memory");
    __builtin_amdgcn_sched_barrier(0);
    __builtin_amdgcn_s_setprio(1);
#pragma unroll
    for (int mf = 0; mf < 4; ++mf)
#pragma unroll
      for (int nf = 0; nf < 2; ++nf)
#pragma unroll
        for (int kk = 0; kk < 2; ++kk)
          acc[mf + 4][nf] = MFMA16(a1[mf][kk], bb[nf][kk], acc[mf + 4][nf]);
    __builtin_amdgcn_s_setprio(0);
    __builtin_amdgcn_sched_barrier(0);
    // ---- phase 4 ----
    stage_half(A, Bt, lds9, 4 * t + 8, mod9(j0 + 8), m0, n0, lda, ldb, kbase, HMAX, tid, wid);
    __builtin_amdgcn_s_setprio(1);
#pragma unroll
    for (int mf = 0; mf < 4; ++mf)
#pragma unroll
      for (int nf = 2; nf < 4; ++nf)
#pragma unroll
        for (int kk = 0; kk < 2; ++kk)
          acc[mf + 4][nf] = MFMA16(a1[mf][kk], bb[nf][kk], acc[mf + 4][nf]);
    __builtin_amdgcn_s_setprio(0);
    __builtin_amdgcn_sched_barrier(0);
    j0 += 4; if (j0 >= 9) j0 -= 9;
  }
#pragma unroll
  for (int mf = 0; mf < 8; ++mf)
#pragma unroll
    for (int nf = 0; nf < 4; ++nf) {
      int col = n0 + wn * 64 + nf * 16 + sl;
      if (col < N) {
#pragma unroll
        for (int r = 0; r < 4; ++r) {
          int row = m0 + wm * 128 + mf * 16 + hi * 4 + r;
          if constexpr (sizeof(TC) == 2)
            Cz[(size_t)row * N + col] = __float2bfloat16(acc[mf][nf][r]);
          else
            Cz[(size_t)row * N + col] = acc[mf][nf][r];
        }
      }
    }
}

// ------------- depthwise conv (SAME, k=4, pad_lo=1) + SiLU, bf16x8 ----------
__global__ __launch_bounds__(256) void conv_silu_k(const bf16* __restrict__ proj,
                                                   const float* __restrict__ cw,
                                                   const float* __restrict__ cb,
                                                   bf16* __restrict__ convo) {
  int idx = blockIdx.x * 256 + threadIdx.x;
  int ci = idx % (CONV_DIM / 8);
  int row = idx / (CONV_DIM / 8);
  int c8 = ci * 8;
  int t = row & (S_LEN - 1);
  int b = row >> 11;
  float acc[8];
  {
    float4 b0 = *reinterpret_cast<const float4*>(&cb[c8]);
    float4 b1 = *reinterpret_cast<const float4*>(&cb[c8 + 4]);
    acc[0] = b0.x; acc[1] = b0.y; acc[2] = b0.z; acc[3] = b0.w;
    acc[4] = b1.x; acc[5] = b1.y; acc[6] = b1.z; acc[7] = b1.w;
  }
#pragma unroll
  for (int w = 0; w < 4; w++) {
    int tt = t + w - 1;
    if (tt >= 0 && tt < S_LEN) {
      U16x8 u;
      u.u = *reinterpret_cast<const uint4*>(
          &proj[(size_t)(b * S_LEN + tt) * PROJ_DIM + INTER + c8]);
      float4 w0 = *reinterpret_cast<const float4*>(&cw[w * CONV_DIM + c8]);
      float4 w1 = *reinterpret_cast<const float4*>(&cw[w * CONV_DIM + c8 + 4]);
      acc[0] += w0.x * bu2f((unsigned short)u.v[0]);
      acc[1] += w0.y * bu2f((unsigned short)u.v[1]);
      acc[2] += w0.z * bu2f((unsigned short)u.v[2]);
      acc[3] += w0.w * bu2f((unsigned short)u.v[3]);
      acc[4] += w1.x * bu2f((unsigned short)u.v[4]);
      acc[5] += w1.y * bu2f((unsigned short)u.v[5]);
      acc[6] += w1.z * bu2f((unsigned short)u.v[6]);
      acc[7] += w1.w * bu2f((unsigned short)u.v[7]);
    }
  }
  uint4 o;
  o.x = pack2(siluf(acc[0]), siluf(acc[1]));
  o.y = pack2(siluf(acc[2]), siluf(acc[3]));
  o.z = pack2(siluf(acc[4]), siluf(acc[5]));
  o.w = pack2(siluf(acc[6]), siluf(acc[7]));
  *reinterpret_cast<uint4*>(&convo[(size_t)row * CONV_DIM + c8]) = o;
}

// ---------------- dt = softplus(dt_raw + dt_bias) ----------------
__global__ __launch_bounds__(256) void dt_k(const bf16* __restrict__ proj,
                                            const float* __restrict__ dtb,
                                            float* __restrict__ dtp) {
  int idx = blockIdx.x * 256 + threadIdx.x;
  int h = idx & 63;
  int row = idx >> 6;
  float x = ldf(&proj[(size_t)row * PROJ_DIM + DT_OFF + h]) + dtb[h];
  dtp[idx] = (x > 20.f) ? x : log1pf(__expf(x));
}

// ---------------- per-chunk cumsum of A[h]*dt ----------------
__global__ __launch_bounds__(256) void acum_k(const float* __restrict__ dtp,
                                              const float* __restrict__ alog,
                                              float* __restrict__ acum) {
  __shared__ float buf[2][CHK];
  int blk = blockIdx.x;
  int c = blk & 7;
  int h = (blk >> 3) & 63;
  int b = blk >> 9;
  int tid = threadIdx.x;
  int row0 = b * S_LEN + c * CHK;
  float a = -__expf(alog[h]);
  buf[0][tid] = a * dtp[(size_t)(row0 + tid) * NH + h];
  __syncthreads();
  int cur = 0;
#pragma unroll
  for (int off = 1; off < 256; off <<= 1) {
    float nv = buf[cur][tid];
    if (tid >= off) nv += buf[cur][tid - off];
    buf[cur ^ 1][tid] = nv;
    cur ^= 1;
    __syncthreads();
  }
  acum[(size_t)blk * CHK + tid] = buf[cur][tid];
}

// ======== per-chunk states via MFMA ====
__global__ __launch_bounds__(256) void chunk_states_mfma(const bf16* __restrict__ convo,
                                                         const float* __restrict__ dtp,
                                                         const float* __restrict__ acum,
                                                         float* __restrict__ cs) {
  __shared__ float sAc[CHK];
  __shared__ float sDtf[CHK];
  __shared__ float sEx[64];
  __shared__ __align__(16) unsigned short sHT[64 * 64];
  __shared__ __align__(16) unsigned short sBd[128 * 64];
  const int tid = threadIdx.x;
  const int lane = tid & 63, hi = lane >> 4, sl = lane & 15;
  const int wid = tid >> 6, wm = wid >> 1, wn = wid & 1;
  const int blk = blockIdx.x;
  const int h = blk & 63, bc = blk >> 6, c = bc & 7, b = bc >> 3, g = h >> 3;
  const int row0 = b * S_LEN + c * CHK;
  sAc[tid] = acum[((size_t)((b * NH + h) * NC + c)) * CHK + tid];
  sDtf[tid] = dtp[(size_t)(row0 + tid) * NH + h];
  f32x4 acc[2][4] = {};
  for (int ts = 0; ts < 4; ++ts) {
    __syncthreads();
    if (tid < 64) sEx[tid] = __expf(sAc[CHK - 1] - sAc[ts * 64 + tid]);
    __syncthreads();
#pragma unroll
    for (int it = 0; it < 2; ++it) {
      int cid = tid + it * 256;
      int t = cid >> 3, p8 = (cid & 7) * 8;
      U16x8 u;
      u.u = *reinterpret_cast<const uint4*>(
          &convo[(size_t)(row0 + ts * 64 + t) * CONV_DIM + h * HD + p8]);
      float dtv = sDtf[ts * 64 + t];
#pragma unroll
      for (int e = 0; e < 8; ++e) {
        int p = p8 + e;
        int G = (p & 7) ^ ((p >> 3) & 7);
        sHT[p * 64 + (((t >> 3) ^ G) * 8) + (t & 7)] =
            f2bu(bu2f((unsigned short)u.v[e]) * dtv);
      }
    }
#pragma unroll
    for (int it = 0; it < 4; ++it) {
      int cid = tid + it * 256;
      int t = cid >> 4, n8 = (cid & 15) * 8;
      U16x8 u;
      u.u = *reinterpret_cast<const uint4*>(
          &convo[(size_t)(row0 + ts * 64 + t) * CONV_DIM + B_OFF + g * SSZ + n8]);
      float ex = sEx[t];
#pragma unroll
      for (int e = 0; e < 8; ++e) {
        int n = n8 + e;
        int G = (n & 7) ^ ((n >> 3) & 7);
        sBd[n * 64 + (((t >> 3) ^ G) * 8) + (t & 7)] =
            f2bu(bu2f((unsigned short)u.v[e]) * ex);
      }
    }
    __syncthreads();
#pragma unroll
    for (int kc = 0; kc < 2; ++kc) {
      bf16x8 a[2], bb[4];
#pragma unroll
      for (int m = 0; m < 2; ++m) {
        int p = wm * 32 + m * 16 + sl;
        int G = (p & 7) ^ ((p >> 3) & 7);
        a[m] = *reinterpret_cast<const bf16x8*>(
            &sHT[p * 64 + (((kc * 4 + hi) ^ G) * 8)]);
      }
#pragma unroll
      for (int j = 0; j < 4; ++j) {
        int n = wn * 64 + j * 16 + sl;
        int G = (n & 7) ^ ((n >> 3) & 7);
        bb[j] = *reinterpret_cast<const bf16x8*>(
            &sBd[n * 64 + (((kc * 4 + hi) ^ G) * 8)]);
      }
#pragma unroll
      for (int m = 0; m < 2; ++m)
#pragma unroll
        for (int j = 0; j < 4; ++j) acc[m][j] = MFMA16(a[m], bb[j], acc[m][j]);
    }
  }
  size_t base = (size_t)blk * HD * SSZ;
#pragma unroll
  for (int m = 0; m < 2; ++m)
#pragma unroll
    for (int j = 0; j < 4; ++j)
#pragma unroll
      for (int r = 0; r < 4; ++r) {
        int p = wm * 32 + m * 16 + hi * 4 + r;
        int n = wn * 64 + j * 16 + sl;
        cs[base + (size_t)p * SSZ + n] = acc[m][j][r];
      }
}

// ---------------- inter-chunk recurrence (in-place) ----------------
__global__ __launch_bounds__(256) void chunk_rec_k(const float* __restrict__ acum,
                                                   float* __restrict__ cs) {
  int idx = blockIdx.x * 256 + threadIdx.x;
  int n = idx & 127;
  int p = (idx >> 7) & 63;
  int h = (idx >> 13) & 63;
  int b = idx >> 19;
  float run = 0.f;
#pragma unroll
  for (int c = 0; c < NC; c++) {
    size_t off = ((size_t)(((b * NC + c) * NH + h) * HD + p)) * SSZ + n;
    float csv = cs[off];
    float al = acum[((size_t)((b * NH + h) * NC + c)) * CHK + (CHK - 1)];
    cs[off] = run;
    run = run * __expf(al) + csv;
  }
}

// ================= chunk output via MFMA (r10 proven form) ===================
__global__ __launch_bounds__(256) void chunk_out_mfma(const bf16* __restrict__ convo,
                                                      const float* __restrict__ dtp,
                                                      const float* __restrict__ acum,
                                                      const float* __restrict__ cs,
                                                      const float* __restrict__ Dp,
                                                      bf16* __restrict__ yb) {
  __shared__ float sAc[CHK];
  __shared__ float sDt[CHK];
  __shared__ __align__(16) unsigned short sB[64 * 128];
  __shared__ __align__(16) unsigned short sH[64 * 64];
  __shared__ __align__(16) unsigned short sW[4 * 64 * 64];
  const int tid = threadIdx.x;
  const int lane = tid & 63, hi = lane >> 4, sl = lane & 15;
  const int wid = tid >> 6;
  const int blk = blockIdx.x;
  const int h = blk & 63;
  const int bc = blk >> 6;
  const int c = bc & 7;
  const int b = bc >> 3;
  const int g = h >> 3;
  const int row0 = b * S_LEN + c * CHK;
  unsigned short* sWp = &sW[wid * 4096];

  sAc[tid] = acum[((size_t)((b * NH + h) * NC + c)) * CHK + tid];
  sDt[tid] = dtp[(size_t)(row0 + tid) * NH + h];

  bf16x8 cf[4][4];
#pragma unroll
  for (int m = 0; m < 4; ++m)
#pragma unroll
    for (int kc = 0; kc < 4; ++kc) {
      int l = wid * 64 + m * 16 + sl;
      U16x8 u;
      u.u = *reinterpret_cast<const uint4*>(
          &convo[(size_t)(row0 + l) * CONV_DIM + C_OFF + g * SSZ + kc * 32 + hi * 8]);
      cf[m][kc] = u.v;
    }

  f32x4 acc[4][4] = {};

  for (int st = 0; st < 4; ++st) {
    __syncthreads();
#pragma unroll
    for (int it = 0; it < 4; ++it) {
      int cid = tid + it * 256;
      int s = cid >> 4, gr = cid & 15;
      const uint4* p = reinterpret_cast<const uint4*>(
          &convo[(size_t)(row0 + st * 64 + s) * CONV_DIM + B_OFF + g * SSZ + gr * 8]);
      *reinterpret_cast<uint4*>(&sB[s * 128 + (gr ^ (s & 7)) * 8]) = *p;
    }
#pragma unroll
    for (int it = 0; it < 16; ++it) {
      int cid = tid + it * 256;
      int s = cid >> 6, pp = cid & 63;
      float v = ldf(&convo[(size_t)(row0 + st * 64 + s) * CONV_DIM + h * HD + pp]) *
                sDt[st * 64 + s];
      sH[pp * 64 + (((s >> 3) ^ (pp & 7)) * 8) + (s & 7)] = f2bu(v);
    }
    __syncthreads();
    if (wid >= st) {
#pragma unroll
      for (int sf = 0; sf < 4; ++sf) {
        f32x4 d[4] = {};
#pragma unroll
        for (int kc = 0; kc < 4; ++kc) {
          int srow = sf * 16 + sl;
          bf16x8 bfv = *reinterpret_cast<const bf16x8*>(
              &sB[srow * 128 + (((kc * 4 + hi) ^ (srow & 7)) * 8)]);
#pragma unroll
          for (int m = 0; m < 4; ++m) d[m] = MFMA16(cf[m][kc], bfv, d[m]);
        }
        int s_loc = sf * 16 + sl;
        int s_glob = st * 64 + s_loc;
        float acS = sAc[s_glob];
        bool diag = (st == wid);
#pragma unroll
        for (int m = 0; m < 4; ++m)
#pragma unroll
          for (int r = 0; r < 4; ++r) {
            int l_loc = m * 16 + hi * 4 + r;
            int l_glob = wid * 64 + l_loc;
            float e = __expf(sAc[l_glob] - acS);
            float v = d[m][r] * e;
            if (diag && s_glob > l_glob) v = 0.f;
            sWp[l_loc * 64 + (((s_loc >> 3) ^ (l_loc & 7)) * 8) + (s_loc & 7)] = f2bu(v);
          }
      }
    }
    __syncthreads();
    if (wid >= st) {
#pragma unroll
      for (int kc = 0; kc < 2; ++kc) {
        bf16x8 a[4], bb[4];
#pragma unroll
        for (int m = 0; m < 4; ++m) {
          int l = m * 16 + sl;
          a[m] = *reinterpret_cast<const bf16x8*>(
              &sWp[l * 64 + (((kc * 4 + hi) ^ (l & 7)) * 8)]);
        }
#pragma unroll
        for (int j = 0; j < 4; ++j) {
          int p = j * 16 + sl;
          bb[j] = *reinterpret_cast<const bf16x8*>(
              &sH[p * 64 + (((kc * 4 + hi) ^ (p & 7)) * 8)]);
        }
#pragma unroll
        for (int m = 0; m < 4; ++m)
#pragma unroll
          for (int j = 0; j < 4; ++j) acc[m][j] = MFMA16(a[m], bb[j], acc[m][j]);
      }
    }
  }

  __syncthreads();
  {
    size_t sinbase = ((size_t)(((b * NC + c) * NH + h) * HD)) * SSZ;
#pragma unroll
    for (int it = 0; it < 8; ++it) {
      int cid = tid + it * 256;
      int p = cid >> 5, q = cid & 31;
      float4 v = *reinterpret_cast<const float4*>(&cs[sinbase + (size_t)p * SSZ + q * 4]);
      uint2 val = make_uint2(pack2(v.x, v.y), pack2(v.z, v.w));
      *reinterpret_cast<uint2*>(&sB[p * 128 + ((q >> 1) ^ (p & 7)) * 8 + (q & 1) * 4]) = val;
    }
  }
  __syncthreads();
#pragma unroll
  for (int m = 0; m < 4; ++m) {
    float e = __expf(sAc[wid * 64 + m * 16 + sl]);
#pragma unroll
    for (int kc = 0; kc < 4; ++kc) {
      bf16x8 fv = cf[m][kc];
#pragma unroll
      for (int ei = 0; ei < 8; ++ei) {
        unsigned short us = (unsigned short)fv[ei];
        fv[ei] = (short)f2bu(bu2f(us) * e);
      }
      cf[m][kc] = fv;
    }
  }
#pragma unroll
  for (int kc = 0; kc < 4; ++kc) {
    bf16x8 bb[4];
#pragma unroll
    for (int j = 0; j < 4; ++j) {
      int p = j * 16 + sl;
      bb[j] = *reinterpret_cast<const bf16x8*>(
          &sB[p * 128 + (((kc * 4 + hi) ^ (p & 7)) * 8)]);
    }
#pragma unroll
    for (int m = 0; m < 4; ++m)
#pragma unroll
      for (int j = 0; j < 4; ++j) acc[m][j] = MFMA16(cf[m][kc], bb[j], acc[m][j]);
  }

  float Dh = Dp[h];
#pragma unroll
  for (int m = 0; m < 4; ++m)
#pragma unroll
    for (int j = 0; j < 4; ++j)
#pragma unroll
      for (int r = 0; r < 4; ++r) {
        int l_glob = wid * 64 + m * 16 + hi * 4 + r;
        size_t row = (size_t)(row0 + l_glob);
        int pg = j * 16 + sl;
        float hraw = ldf(&convo[row * CONV_DIM + h * HD + pg]);
        yb[row * YSTR + h * HD + pg] = __float2bfloat16(acc[m][j][r] + Dh * hraw);
      }
}

// ------------- gate SiLU + RMSNorm (in-place on yb), bf16x8 -------------
__global__ __launch_bounds__(256) void norm_k(const bf16* __restrict__ proj,
                                              const float* __restrict__ nw,
                                              bf16* __restrict__ yb) {
  int row = blockIdx.x;
  int tid = threadIdx.x;
  float vals[16];
  float ss = 0.f;
#pragma unroll
  for (int half = 0; half < 2; half++) {
    int colb = tid * 8 + half * 2048;
    U16x8 gy, gg;
    gy.u = *reinterpret_cast<const uint4*>(&yb[(size_t)row * YSTR + colb]);
    gg.u = *reinterpret_cast<const uint4*>(&proj[(size_t)row * PROJ_DIM + colb]);
#pragma unroll
    for (int e = 0; e < 8; e++) {
      float yf = bu2f((unsigned short)gy.v[e]) * siluf(bu2f((unsigned short)gg.v[e]));
      vals[half * 8 + e] = yf;
      ss += yf * yf;
    }
  }
#pragma unroll
  for (int off = 32; off > 0; off >>= 1) ss += __shfl_down(ss, off);
  __shared__ float red[4];
  if ((tid & 63) == 0) red[tid >> 6] = ss;
  __syncthreads();
  float tot = red[0] + red[1] + red[2] + red[3];
  float scale = rsqrtf(tot * (1.f / INTER) + 1e-6f);
#pragma unroll
  for (int half = 0; half < 2; half++) {
    int colb = tid * 8 + half * 2048;
    float4 w0 = *reinterpret_cast<const float4*>(&nw[colb]);
    float4 w1 = *reinterpret_cast<const float4*>(&nw[colb + 4]);
    float s0 = vals[half * 8 + 0] * scale * w0.x, s1 = vals[half * 8 + 1] * scale * w0.y;
    float s2 = vals[half * 8 + 2] * scale * w0.z, s3 = vals[half * 8 + 3] * scale * w0.w;
    float s4 = vals[half * 8 + 4] * scale * w1.x, s5 = vals[half * 8 + 5] * scale * w1.y;
    float s6 = vals[half * 8 + 6] * scale * w1.z, s7 = vals[half * 8 + 7] * scale * w1.w;
    uint4 o = make_uint4(pack2(s0, s1), pack2(s2, s3), pack2(s4, s5), pack2(s6, s7));
    *reinterpret_cast<uint4*>(&yb[(size_t)row * YSTR + colb]) = o;
  }
}

extern "C" void kernel_launch(void* const* d_in, const int* in_sizes, int n_in,
                              void* d_out, int out_size, void* d_ws, size_t ws_size,
                              hipStream_t stream) {
  const float* x     = (const float*)d_in[0];
  const float* wproj = (const float*)d_in[1];
  const float* cw    = (const float*)d_in[2];
  const float* cb    = (const float*)d_in[3];
  const float* dtb   = (const float*)d_in[4];
  const float* alog  = (const float*)d_in[5];
  const float* Dp    = (const float*)d_in[6];
  const float* nw    = (const float*)d_in[7];
  const float* wout  = (const float*)d_in[8];
  float* out = (float*)d_out;
  char* ws = (char*)d_ws;

  // workspace layout (~195.0 MiB)
  bf16*  proj  = (bf16*)(ws);                    // 84,410,368 B
  bf16*  convo = (bf16*)(ws + 84410368);         // 50,331,648 B
  bf16*  yb    = (bf16*)(ws + 134742016);        // 34,078,720 B (4096 x YSTR)
  float* dtp   = (float*)(ws + 168820736);       //  1,048,576 B
  float* acum  = (float*)(ws + 169869312);       //  1,048,576 B
  float* cs    = (float*)(ws + 170917888);       // 33,554,432 B  (end 204,472,320)
  // liveness-overlapped temporaries:
  unsigned short* Wt1 = (unsigned short*)(ws + 84410368);   // in convo (44.3MB < 50.3MB)
  unsigned short* xb  = (unsigned short*)(ws + 134742016);  // in yb (17.3MB < 34.1MB)
  unsigned short* Wt2 = (unsigned short*)(ws + 170917888);  // in cs (17.0MB < 33.6MB)
  float* part = (float*)(ws);   // split-K partials in proj region (67MB < 84MB)

  hipFuncSetAttribute(reinterpret_cast<const void*>(&gemm_8ph<bf16>),
                      hipFuncAttributeMaxDynamicSharedMemorySize, 147456);
  hipFuncSetAttribute(reinterpret_cast<const void*>(&gemm_8ph<float>),
                      hipFuncAttributeMaxDynamicSharedMemorySize, 147456);

  cvt_pad_k<<<dim3(4096), 256, 0, stream>>>(x, xb);
  wT_k<<<dim3(PROJ_PAD / 64, HIDDEN / 64), 256, 0, stream>>>(wproj, Wt1, HIDDEN, PROJ_DIM, XSTR);
  gemm_8ph<bf16><<<dim3(PROJ_PAD / 256, ROWS / 256, 1), 512, 147456, stream>>>(
      xb, Wt1, proj, ROWS, PROJ_DIM, HIDDEN, HIDDEN, XSTR, XSTR);
  conv_silu_k<<<dim3(ROWS * CONV_DIM / 8 / 256), 256, 0, stream>>>(proj, cw, cb, convo);
  dt_k<<<dim3(ROWS * NH / 256), 256, 0, stream>>>(proj, dtb, dtp);
  acum_k<<<dim3(2 * NH * NC), 256, 0, stream>>>(dtp, alog, acum);
  chunk_states_mfma<<<dim3(2 * NC * NH), 256, 0, stream>>>(convo, dtp, acum, cs);
  chunk_rec_k<<<dim3(2 * NH * HD * SSZ / 256), 256, 0, stream>>>(acum, cs);
  chunk_out_mfma<<<dim3(2 * NC * NH), 256, 0, stream>>>(convo, dtp, acum, cs, Dp, yb);
  norm_k<<<dim3(ROWS), 256, 0, stream>>>(proj, nw, yb);
  wT_k<<<dim3(HIDDEN / 64, INTER / 64), 256, 0, stream>>>(wout, Wt2, INTER, HIDDEN, YSTR);
  // out-proj: split-K=2 over 256 blocks, fp32 partials, then reduce
  gemm_8ph<float><<<dim3(HIDDEN / 256, ROWS / 256, 2), 512, 147456, stream>>>(
      (const unsigned short*)yb, Wt2, part, ROWS, HIDDEN, INTER, INTER / 2, YSTR, YSTR);
  add_k<<<dim3(2048), 256, 0, stream>>>(part, part + (size_t)ROWS * HIDDEN, out,
                                        ROWS * HIDDEN / 4);
}